// Round 1
// baseline (6043.321 us; speedup 1.0000x reference)
//
#include <hip/hip_runtime.h>

// GAT layer: B=2, N=50000, D=64, H=4, d=16, O=64, E=800000
#define N_NODES 50000
#define N_EDGES 800000
#define NEG_SLOPE 0.1f

// ws layout (floats):
//  feat  [N][B][H][d] : 6,400,000
//  el    [N][B*H]     :   400,000
//  er    [N][B*H]     :   400,000
//  denom [N][B*H]     :   400,000   (zeroed each launch)
//  rst   [N][B][H][d] : 6,400,000   (zeroed each launch)
// total 14,000,000 floats = 56 MB

static __device__ __forceinline__ void atomic_add_f32(float* p, float v) {
    __hip_atomic_fetch_add(p, v, __ATOMIC_RELAXED, __HIP_MEMORY_SCOPE_AGENT);
}

// ---- Kernel 1: feat = x @ W_fc.T  (+ fused el/er logits) --------------------
// grid 25000 x 256: 4 rows (b,n) per block, thread j computes output col j.
__global__ __launch_bounds__(256) void k_fc(const float* __restrict__ x,
                                            const float* __restrict__ Wfc,
                                            const float* __restrict__ al,
                                            const float* __restrict__ ar,
                                            float* __restrict__ feat,
                                            float* __restrict__ el,
                                            float* __restrict__ er) {
    __shared__ float Ws[64 * 65];   // +1 pad: lanes hit distinct banks in k-loop
    __shared__ float xs[4 * 64];
    const int t = threadIdx.x;
#pragma unroll
    for (int i = 0; i < 16; ++i) {  // stage W_fc (4096 floats), coalesced
        int p = i * 256 + t;
        Ws[(p >> 6) * 65 + (p & 63)] = Wfc[p];
    }
    const int r = t >> 6, j = t & 63;
    const int m = blockIdx.x * 4 + r;          // m = b*N + n, exact (100000/4)
    xs[r * 64 + j] = x[m * 64 + j];
    __syncthreads();

    float acc = 0.f;
#pragma unroll
    for (int k = 0; k < 64; ++k)
        acc = fmaf(xs[r * 64 + k], Ws[j * 65 + k], acc);

    const int b = m / N_NODES, n = m % N_NODES;
    feat[n * 128 + b * 64 + j] = acc;

    float pl = acc * al[j];
    float pr = acc * ar[j];
#pragma unroll
    for (int off = 1; off < 16; off <<= 1) {   // reduce over d=16 lanes
        pl += __shfl_xor(pl, off, 16);
        pr += __shfl_xor(pr, off, 16);
    }
    if ((j & 15) == 0) {
        const int h = j >> 4;
        el[n * 8 + b * 4 + h] = pl;
        er[n * 8 + b * 4 + h] = pr;
    }
}

// ---- Kernel 2: edge pass — ex = exp(w*leaky(el[s]+er[t])); scatter ----------
// one thread per (edge, b, h): 6.4M items, grid 25000 x 256.
__global__ __launch_bounds__(256) void k_edge(const int* __restrict__ src,
                                              const int* __restrict__ dst,
                                              const float* __restrict__ w,
                                              const float* __restrict__ el,
                                              const float* __restrict__ er,
                                              const float* __restrict__ feat,
                                              float* __restrict__ denom,
                                              float* __restrict__ rst) {
    const int gid = blockIdx.x * 256 + threadIdx.x;
    const int e = gid >> 3, c = gid & 7;       // c = b*4 + h
    const int s = src[e], t = dst[e];
    float z = el[s * 8 + c] + er[t * 8 + c];
    z = (z > 0.f) ? z : NEG_SLOPE * z;
    const float ex = __expf(w[e] * z);         // no max-shift needed: scores tiny
    atomic_add_f32(&denom[t * 8 + c], ex);

    const float4* fs = reinterpret_cast<const float4*>(feat + s * 128 + c * 16);
    float* rd = rst + t * 128 + c * 16;
    const float4 f0 = fs[0], f1 = fs[1], f2 = fs[2], f3 = fs[3];
    atomic_add_f32(rd + 0,  ex * f0.x);
    atomic_add_f32(rd + 1,  ex * f0.y);
    atomic_add_f32(rd + 2,  ex * f0.z);
    atomic_add_f32(rd + 3,  ex * f0.w);
    atomic_add_f32(rd + 4,  ex * f1.x);
    atomic_add_f32(rd + 5,  ex * f1.y);
    atomic_add_f32(rd + 6,  ex * f1.z);
    atomic_add_f32(rd + 7,  ex * f1.w);
    atomic_add_f32(rd + 8,  ex * f2.x);
    atomic_add_f32(rd + 9,  ex * f2.y);
    atomic_add_f32(rd + 10, ex * f2.z);
    atomic_add_f32(rd + 11, ex * f2.w);
    atomic_add_f32(rd + 12, ex * f3.x);
    atomic_add_f32(rd + 13, ex * f3.y);
    atomic_add_f32(rd + 14, ex * f3.z);
    atomic_add_f32(rd + 15, ex * f3.w);
}

// ---- Kernel 3: out = (rst/denom) @ W_out.T + b_out, layout [B,N,H,O] --------
// grid 100000 x 256: 4 groups g=(n,b,h) per block, thread o computes output o.
__global__ __launch_bounds__(256) void k_out(const float* __restrict__ rst,
                                             const float* __restrict__ denom,
                                             const float* __restrict__ Wout,
                                             const float* __restrict__ bout,
                                             float* __restrict__ out) {
    __shared__ float Wo[64 * 17];   // +1 pad breaks the o*16 bank aliasing
    __shared__ float rs[64];
    __shared__ float dn[4];
    const int t = threadIdx.x;
#pragma unroll
    for (int i = 0; i < 4; ++i) {   // stage W_out (1024 floats)
        int p = i * 256 + t;
        Wo[(p >> 4) * 17 + (p & 15)] = Wout[p];
    }
    if (t < 64) rs[t] = rst[blockIdx.x * 64 + t];
    if (t < 4)  dn[t] = denom[blockIdx.x * 4 + t];
    __syncthreads();

    const int r = t >> 6, o = t & 63;
    const int g = blockIdx.x * 4 + r;          // g = n*8 + b*4 + h
    const float d = dn[r];
    const float dinv = (d > 0.f) ? 1.f / d : 0.f;   // empty-dst node -> b_out
    float acc = 0.f;
#pragma unroll
    for (int k = 0; k < 16; ++k)
        acc = fmaf(rs[r * 16 + k], Wo[o * 17 + k], acc);
    acc = fmaf(acc, dinv, bout[o]);

    const int n = g >> 3, b = (g >> 2) & 1, h = g & 3;
    out[b * (N_NODES * 256) + n * 256 + h * 64 + o] = acc;
}

extern "C" void kernel_launch(void* const* d_in, const int* in_sizes, int n_in,
                              void* d_out, int out_size, void* d_ws, size_t ws_size,
                              hipStream_t stream) {
    // setup_inputs order: vt, x, w, src, dst, W_fc, attn_l, attn_r, W_out, b_out
    const float* x    = (const float*)d_in[1];
    const float* w    = (const float*)d_in[2];
    const int*   src  = (const int*)  d_in[3];
    const int*   dst  = (const int*)  d_in[4];
    const float* Wfc  = (const float*)d_in[5];
    const float* al   = (const float*)d_in[6];
    const float* ar   = (const float*)d_in[7];
    const float* Wout = (const float*)d_in[8];
    const float* bout = (const float*)d_in[9];
    float* out = (float*)d_out;

    float* ws    = (float*)d_ws;
    float* feat  = ws;                  // 6,400,000
    float* el    = feat + 6400000;      //   400,000
    float* er    = el + 400000;         //   400,000
    float* denom = er + 400000;         //   400,000
    float* rst   = denom + 400000;      // 6,400,000

    // zero the accumulators (denom + rst are contiguous)
    hipMemsetAsync(denom, 0, (400000 + 6400000) * sizeof(float), stream);

    k_fc<<<25000, 256, 0, stream>>>(x, Wfc, al, ar, feat, el, er);
    k_edge<<<25000, 256, 0, stream>>>(src, dst, w, el, er, feat, denom, rst);
    k_out<<<100000, 256, 0, stream>>>(rst, denom, Wout, bout, out);
}

// Round 2
// 603.405 us; speedup vs baseline: 10.0154x; 10.0154x over previous
//
#include <hip/hip_runtime.h>

// GAT layer: B=2, N=50000, D=64, H=4, d=16, O=64, E=800000
#define N_NODES 50000
#define N_EDGES 800000
#define NEG_SLOPE 0.1f

// ws layout:
//  feat    [N][B][H][d] : 6,400,000 f32
//  el      [N][B*H]     :   400,000 f32
//  er      [N][B*H]     :   400,000 f32
//  denom   [N][B*H]     :   400,000 f32
//  rst     [N][B][H][d] : 6,400,000 f32
//  offsets [N+1]        :    50,004 i32
//  cursor  [N]          :    50,000 i32
//  deg     [N]          :    50,000 i32   (zeroed each launch)
//  srcw    [E]          :   800,000 int2  (dst-sorted (src, w) pairs)
// total ~63 MB

// ---- Kernel 1: feat = x @ W_fc.T  (+ fused el/er logits) --------------------
__global__ __launch_bounds__(256) void k_fc(const float* __restrict__ x,
                                            const float* __restrict__ Wfc,
                                            const float* __restrict__ al,
                                            const float* __restrict__ ar,
                                            float* __restrict__ feat,
                                            float* __restrict__ el,
                                            float* __restrict__ er) {
    __shared__ float Ws[64 * 65];
    __shared__ float xs[4 * 64];
    const int t = threadIdx.x;
#pragma unroll
    for (int i = 0; i < 16; ++i) {
        int p = i * 256 + t;
        Ws[(p >> 6) * 65 + (p & 63)] = Wfc[p];
    }
    const int r = t >> 6, j = t & 63;
    const int m = blockIdx.x * 4 + r;          // m = b*N + n
    xs[r * 64 + j] = x[m * 64 + j];
    __syncthreads();

    float acc = 0.f;
#pragma unroll
    for (int k = 0; k < 64; ++k)
        acc = fmaf(xs[r * 64 + k], Ws[j * 65 + k], acc);

    const int b = m / N_NODES, n = m % N_NODES;
    feat[n * 128 + b * 64 + j] = acc;

    float pl = acc * al[j];
    float pr = acc * ar[j];
#pragma unroll
    for (int off = 1; off < 16; off <<= 1) {
        pl += __shfl_xor(pl, off, 16);
        pr += __shfl_xor(pr, off, 16);
    }
    if ((j & 15) == 0) {
        const int h = j >> 4;
        el[n * 8 + b * 4 + h] = pl;
        er[n * 8 + b * 4 + h] = pr;
    }
}

// ---- CSR build: histogram -> scan -> scatter --------------------------------
__global__ __launch_bounds__(256) void k_hist(const int* __restrict__ dst,
                                              int* __restrict__ deg) {
    const int e = blockIdx.x * 256 + threadIdx.x;   // grid exact: 800000/256
    atomicAdd(&deg[dst[e]], 1);
}

#define SCAN_T 1024
#define SCAN_CHUNK 49   // ceil(50000/1024)
__global__ __launch_bounds__(SCAN_T) void k_scan(const int* __restrict__ deg,
                                                 int* __restrict__ offsets,
                                                 int* __restrict__ cursor) {
    __shared__ int lds[SCAN_T];
    const int t = threadIdx.x;
    const int s0 = t * SCAN_CHUNK;
    const int s1 = min(s0 + SCAN_CHUNK, N_NODES);
    int sum = 0;
    for (int i = s0; i < s1; ++i) sum += deg[i];
    lds[t] = sum;
    __syncthreads();
    for (int off = 1; off < SCAN_T; off <<= 1) {
        int add = (t >= off) ? lds[t - off] : 0;
        __syncthreads();
        lds[t] += add;
        __syncthreads();
    }
    int run = (t > 0) ? lds[t - 1] : 0;
    for (int i = s0; i < s1; ++i) {
        offsets[i] = run;
        cursor[i] = run;
        run += deg[i];
    }
    if (t == 0) offsets[N_NODES] = N_EDGES;
}

__global__ __launch_bounds__(256) void k_scatter(const int* __restrict__ src,
                                                 const int* __restrict__ dst,
                                                 const float* __restrict__ w,
                                                 int* __restrict__ cursor,
                                                 int2* __restrict__ srcw) {
    const int e = blockIdx.x * 256 + threadIdx.x;
    const int tn = dst[e];
    const int pos = atomicAdd(&cursor[tn], 1);
    srcw[pos] = make_int2(src[e], __float_as_int(w[e]));
}

// ---- Kernel 2: per-dst gather — softmax numerator + weighted sum ------------
// 2 nodes per 256-thread block; 128 threads per node: thread = (c=i>>4, j=i&15)
__global__ __launch_bounds__(256) void k_gather(const int2* __restrict__ srcw,
                                                const int* __restrict__ offsets,
                                                const float* __restrict__ el,
                                                const float* __restrict__ er,
                                                const float* __restrict__ feat,
                                                float* __restrict__ denom,
                                                float* __restrict__ rst) {
    const int t = threadIdx.x;
    const int half = t >> 7;
    const int lt = t & 127;
    const int c = lt >> 4, j = lt & 15;
    const int n = blockIdx.x * 2 + half;       // grid exact: 50000/2
    const int beg = offsets[n], end = offsets[n + 1];
    const float ern = er[n * 8 + c];
    float acc = 0.f, den = 0.f;
    for (int k = beg; k < end; ++k) {
        const int2 sw = srcw[k];               // uniform per half-block
        const int s = sw.x;
        const float wv = __int_as_float(sw.y);
        float z = el[s * 8 + c] + ern;
        z = (z > 0.f) ? z : NEG_SLOPE * z;
        const float ex = __expf(wv * z);
        den += ex;
        acc += ex * feat[s * 128 + lt];        // coalesced 512B per edge
    }
    rst[n * 128 + lt] = acc;
    if (j == 0) denom[n * 8 + c] = den;
}

// ---- Kernel 3: out = (rst/denom) @ W_out.T + b_out, layout [B,N,H,O] --------
__global__ __launch_bounds__(256) void k_out(const float* __restrict__ rst,
                                             const float* __restrict__ denom,
                                             const float* __restrict__ Wout,
                                             const float* __restrict__ bout,
                                             float* __restrict__ out) {
    __shared__ float Wo[64 * 17];
    __shared__ float rs[64];
    __shared__ float dn[4];
    const int t = threadIdx.x;
#pragma unroll
    for (int i = 0; i < 4; ++i) {
        int p = i * 256 + t;
        Wo[(p >> 4) * 17 + (p & 15)] = Wout[p];
    }
    if (t < 64) rs[t] = rst[blockIdx.x * 64 + t];
    if (t < 4)  dn[t] = denom[blockIdx.x * 4 + t];
    __syncthreads();

    const int r = t >> 6, o = t & 63;
    const int g = blockIdx.x * 4 + r;          // g = n*8 + b*4 + h
    const float d = dn[r];
    const float dinv = (d > 0.f) ? 1.f / d : 0.f;
    float acc = 0.f;
#pragma unroll
    for (int k = 0; k < 16; ++k)
        acc = fmaf(rs[r * 16 + k], Wo[o * 17 + k], acc);
    acc = fmaf(acc, dinv, bout[o]);

    const int n = g >> 3, b = (g >> 2) & 1, h = g & 3;
    out[b * (N_NODES * 256) + n * 256 + h * 64 + o] = acc;
}

extern "C" void kernel_launch(void* const* d_in, const int* in_sizes, int n_in,
                              void* d_out, int out_size, void* d_ws, size_t ws_size,
                              hipStream_t stream) {
    // setup_inputs order: vt, x, w, src, dst, W_fc, attn_l, attn_r, W_out, b_out
    const float* x    = (const float*)d_in[1];
    const float* w    = (const float*)d_in[2];
    const int*   src  = (const int*)  d_in[3];
    const int*   dst  = (const int*)  d_in[4];
    const float* Wfc  = (const float*)d_in[5];
    const float* al   = (const float*)d_in[6];
    const float* ar   = (const float*)d_in[7];
    const float* Wout = (const float*)d_in[8];
    const float* bout = (const float*)d_in[9];
    float* out = (float*)d_out;

    float* ws    = (float*)d_ws;
    float* feat  = ws;                  // 6,400,000 f32
    float* el    = feat + 6400000;      //   400,000
    float* er    = el + 400000;         //   400,000
    float* denom = er + 400000;         //   400,000
    float* rst   = denom + 400000;      // 6,400,000
    int*   offsets = (int*)(rst + 6400000);   // 50,004 (N+1, padded)
    int*   cursor  = offsets + 50004;         // 50,000
    int*   deg     = cursor + 50000;          // 50,000
    int2*  srcw    = (int2*)(deg + 50000);    // 800,000 int2

    hipMemsetAsync(deg, 0, N_NODES * sizeof(int), stream);

    k_fc<<<25000, 256, 0, stream>>>(x, Wfc, al, ar, feat, el, er);
    k_hist<<<N_EDGES / 256, 256, 0, stream>>>(dst, deg);
    k_scan<<<1, SCAN_T, 0, stream>>>(deg, offsets, cursor);
    k_scatter<<<N_EDGES / 256, 256, 0, stream>>>(src, dst, w, cursor, srcw);
    k_gather<<<N_NODES / 2, 256, 0, stream>>>(srcw, offsets, el, er, feat, denom, rst);
    k_out<<<100000, 256, 0, stream>>>(rst, denom, Wout, bout, out);
}

// Round 3
// 378.717 us; speedup vs baseline: 15.9573x; 1.5933x over previous
//
#include <hip/hip_runtime.h>

// GAT layer: B=2, N=50000, D=64, H=4, d=16, O=64, E=800000
#define N_NODES 50000
#define N_EDGES 800000
#define NEG_SLOPE 0.1f

static __device__ __forceinline__ float lrelu(float z) {
    return (z > 0.f) ? z : NEG_SLOPE * z;
}

// ws layout (floats):
//  feat    [N][B][H][d] : 6,400,000
//  el      [N][B*H]     :   400,000
//  er      [N][B*H]     :   400,000
//  denom   [N][B*H]     :   400,000
//  rst     [N][B][H][d] : 6,400,000
//  offsets [N] i32, cursor [N] i32, deg [N] i32, gctr [16] i32
//  srcw    [E] int2  (dst-grouped (src, w) pairs; group order arbitrary)

// ---- Kernel 1: feat = x @ W_fc.T (+ fused el/er) ----------------------------
// grid 6250: 16 rows/block; thread (rr=t>>6, j=t&63) computes 4 rows' col j.
__global__ __launch_bounds__(256) void k_fc(const float* __restrict__ x,
                                            const float* __restrict__ Wfc,
                                            const float* __restrict__ al,
                                            const float* __restrict__ ar,
                                            float* __restrict__ feat,
                                            float* __restrict__ el,
                                            float* __restrict__ er) {
    __shared__ float Ws[64 * 68];   // pad 68: 16B-aligned float4 rows, conflict-free
    __shared__ float xs[16 * 64];
    const int t = threadIdx.x;
#pragma unroll
    for (int i = 0; i < 16; ++i) {
        int p = i * 256 + t;
        Ws[(p >> 6) * 68 + (p & 63)] = Wfc[p];
    }
#pragma unroll
    for (int i = 0; i < 4; ++i) {
        int p = i * 256 + t;
        xs[p] = x[blockIdx.x * 1024 + p];
    }
    __syncthreads();

    const int j = t & 63, rr = t >> 6;
    float a0 = 0.f, a1 = 0.f, a2 = 0.f, a3 = 0.f;
#pragma unroll
    for (int k4 = 0; k4 < 16; ++k4) {
        const float4 wv = *(const float4*)&Ws[j * 68 + k4 * 4];
        const float4 x0 = *(const float4*)&xs[(rr * 4 + 0) * 64 + k4 * 4];
        const float4 x1 = *(const float4*)&xs[(rr * 4 + 1) * 64 + k4 * 4];
        const float4 x2 = *(const float4*)&xs[(rr * 4 + 2) * 64 + k4 * 4];
        const float4 x3 = *(const float4*)&xs[(rr * 4 + 3) * 64 + k4 * 4];
        a0 = fmaf(x0.x, wv.x, a0); a0 = fmaf(x0.y, wv.y, a0);
        a0 = fmaf(x0.z, wv.z, a0); a0 = fmaf(x0.w, wv.w, a0);
        a1 = fmaf(x1.x, wv.x, a1); a1 = fmaf(x1.y, wv.y, a1);
        a1 = fmaf(x1.z, wv.z, a1); a1 = fmaf(x1.w, wv.w, a1);
        a2 = fmaf(x2.x, wv.x, a2); a2 = fmaf(x2.y, wv.y, a2);
        a2 = fmaf(x2.z, wv.z, a2); a2 = fmaf(x2.w, wv.w, a2);
        a3 = fmaf(x3.x, wv.x, a3); a3 = fmaf(x3.y, wv.y, a3);
        a3 = fmaf(x3.z, wv.z, a3); a3 = fmaf(x3.w, wv.w, a3);
    }
    const float alj = al[j], arj = ar[j];
    const float acc[4] = {a0, a1, a2, a3};
#pragma unroll
    for (int i = 0; i < 4; ++i) {
        const int m = blockIdx.x * 16 + rr * 4 + i;   // m = b*N + n
        const int b = m / N_NODES, n = m - b * N_NODES;
        feat[n * 128 + b * 64 + j] = acc[i];
        float pl = acc[i] * alj, pr = acc[i] * arj;
#pragma unroll
        for (int off = 1; off < 16; off <<= 1) {
            pl += __shfl_xor(pl, off, 16);
            pr += __shfl_xor(pr, off, 16);
        }
        if ((j & 15) == 0) {
            el[n * 8 + b * 4 + (j >> 4)] = pl;
            er[n * 8 + b * 4 + (j >> 4)] = pr;
        }
    }
}

// ---- CSR build --------------------------------------------------------------
__global__ __launch_bounds__(256) void k_hist(const int* __restrict__ dst,
                                              int* __restrict__ deg) {
    const int e = blockIdx.x * 256 + threadIdx.x;   // grid exact 800000/256
    atomicAdd(&deg[dst[e]], 1);
}

// wave-aggregated base allocation: no global scan, group order arbitrary
__global__ __launch_bounds__(256) void k_alloc(const int* __restrict__ deg,
                                               int* __restrict__ offsets,
                                               int* __restrict__ cursor,
                                               int* __restrict__ gctr) {
    const int i = blockIdx.x * 256 + threadIdx.x;   // grid 196 covers 50176
    const int lane = threadIdx.x & 63;
    const int d = (i < N_NODES) ? deg[i] : 0;
    int incl = d;
#pragma unroll
    for (int off = 1; off < 64; off <<= 1) {
        int v = __shfl_up(incl, off, 64);
        if (lane >= off) incl += v;
    }
    const int wtot = __shfl(incl, 63, 64);
    int wbase = 0;
    if (lane == 63) wbase = atomicAdd(gctr, wtot);
    wbase = __shfl(wbase, 63, 64);
    if (i < N_NODES) {
        const int beg = wbase + incl - d;
        offsets[i] = beg;
        cursor[i] = beg;
    }
}

__global__ __launch_bounds__(256) void k_scatter(const int* __restrict__ src,
                                                 const int* __restrict__ dst,
                                                 const float* __restrict__ w,
                                                 int* __restrict__ cursor,
                                                 int2* __restrict__ srcw) {
    const int e = blockIdx.x * 256 + threadIdx.x;
    const int pos = atomicAdd(&cursor[dst[e]], 1);
    srcw[pos] = make_int2(src[e], __float_as_int(w[e]));
}

// ---- Kernel 2: per-dst gather — softmax numerator + weighted sum ------------
// 32 threads/node, 8 nodes per 256-block; thread handles float4 (sub in [0,32))
__global__ __launch_bounds__(256) void k_gather(const int2* __restrict__ srcw,
                                                const int* __restrict__ offsets,
                                                const int* __restrict__ deg,
                                                const float* __restrict__ el,
                                                const float* __restrict__ er,
                                                const float* __restrict__ feat,
                                                float* __restrict__ denom,
                                                float* __restrict__ rst) {
    const int t = threadIdx.x;
    const int n = blockIdx.x * 8 + (t >> 5);   // grid exact 50000/8
    const int sub = t & 31, c = sub >> 2;
    const int beg = offsets[n], len = deg[n];
    const float ern = er[n * 8 + c];
    const float4* feat4 = (const float4*)feat;
    float4 acc = make_float4(0.f, 0.f, 0.f, 0.f);
    float den = 0.f;
    int k = 0;
    for (; k + 2 <= len; k += 2) {             // 2-way unroll: 2 load chains
        const int2 s0 = srcw[beg + k];
        const int2 s1 = srcw[beg + k + 1];
        const float e0 = el[s0.x * 8 + c];
        const float e1 = el[s1.x * 8 + c];
        const float4 f0 = feat4[s0.x * 32 + sub];
        const float4 f1 = feat4[s1.x * 32 + sub];
        const float x0 = __expf(__int_as_float(s0.y) * lrelu(e0 + ern));
        const float x1 = __expf(__int_as_float(s1.y) * lrelu(e1 + ern));
        den += x0 + x1;
        acc.x = fmaf(x0, f0.x, acc.x); acc.y = fmaf(x0, f0.y, acc.y);
        acc.z = fmaf(x0, f0.z, acc.z); acc.w = fmaf(x0, f0.w, acc.w);
        acc.x = fmaf(x1, f1.x, acc.x); acc.y = fmaf(x1, f1.y, acc.y);
        acc.z = fmaf(x1, f1.z, acc.z); acc.w = fmaf(x1, f1.w, acc.w);
    }
    if (k < len) {
        const int2 s0 = srcw[beg + k];
        const float e0 = el[s0.x * 8 + c];
        const float4 f0 = feat4[s0.x * 32 + sub];
        const float x0 = __expf(__int_as_float(s0.y) * lrelu(e0 + ern));
        den += x0;
        acc.x = fmaf(x0, f0.x, acc.x); acc.y = fmaf(x0, f0.y, acc.y);
        acc.z = fmaf(x0, f0.z, acc.z); acc.w = fmaf(x0, f0.w, acc.w);
    }
    ((float4*)rst)[n * 32 + sub] = acc;
    if ((sub & 3) == 0) denom[n * 8 + c] = den;
}

// ---- Kernel 3: out = (rst/denom) @ W_out.T + b_out, layout [B,N,H,O] --------
// grid 6250: 64 groups/block; W_out row in registers, rs via LDS broadcast b128
__global__ __launch_bounds__(256) void k_out(const float* __restrict__ rst,
                                             const float* __restrict__ denom,
                                             const float* __restrict__ Wout,
                                             const float* __restrict__ bout,
                                             float* __restrict__ out) {
    __shared__ float rs[1024];
    __shared__ float dn[64];
    const int t = threadIdx.x;
    const int o = t & 63, r = t >> 6;
#pragma unroll
    for (int i = 0; i < 4; ++i)
        rs[i * 256 + t] = rst[blockIdx.x * 1024 + i * 256 + t];
    if (t < 64) dn[t] = denom[blockIdx.x * 64 + t];
    __syncthreads();

    const float4* Wo4 = (const float4*)Wout;
    const float4 wa = Wo4[o * 4 + 0], wb = Wo4[o * 4 + 1];
    const float4 wc = Wo4[o * 4 + 2], wd = Wo4[o * 4 + 3];
    const float bo = bout[o];
#pragma unroll
    for (int i = 0; i < 16; ++i) {
        const int gl = i * 4 + r;              // local g, 0..63
        const float dv = dn[gl];
        const float dinv = (dv > 0.f) ? 1.f / dv : 0.f;
        const float4* r4 = (const float4*)&rs[gl * 16];
        const float4 ra = r4[0], rb = r4[1], rc = r4[2], rd = r4[3];
        float acc = ra.x * wa.x;
        acc = fmaf(ra.y, wa.y, acc); acc = fmaf(ra.z, wa.z, acc); acc = fmaf(ra.w, wa.w, acc);
        acc = fmaf(rb.x, wb.x, acc); acc = fmaf(rb.y, wb.y, acc);
        acc = fmaf(rb.z, wb.z, acc); acc = fmaf(rb.w, wb.w, acc);
        acc = fmaf(rc.x, wc.x, acc); acc = fmaf(rc.y, wc.y, acc);
        acc = fmaf(rc.z, wc.z, acc); acc = fmaf(rc.w, wc.w, acc);
        acc = fmaf(rd.x, wd.x, acc); acc = fmaf(rd.y, wd.y, acc);
        acc = fmaf(rd.z, wd.z, acc); acc = fmaf(rd.w, wd.w, acc);
        acc = fmaf(acc, dinv, bo);
        const int g = blockIdx.x * 64 + gl;    // g = n*8 + b*4 + h
        const int n = g >> 3, b = (g >> 2) & 1, h = g & 3;
        out[b * (N_NODES * 256) + n * 256 + h * 64 + o] = acc;
    }
}

extern "C" void kernel_launch(void* const* d_in, const int* in_sizes, int n_in,
                              void* d_out, int out_size, void* d_ws, size_t ws_size,
                              hipStream_t stream) {
    // setup_inputs order: vt, x, w, src, dst, W_fc, attn_l, attn_r, W_out, b_out
    const float* x    = (const float*)d_in[1];
    const float* w    = (const float*)d_in[2];
    const int*   src  = (const int*)  d_in[3];
    const int*   dst  = (const int*)  d_in[4];
    const float* Wfc  = (const float*)d_in[5];
    const float* al   = (const float*)d_in[6];
    const float* ar   = (const float*)d_in[7];
    const float* Wout = (const float*)d_in[8];
    const float* bout = (const float*)d_in[9];
    float* out = (float*)d_out;

    float* ws    = (float*)d_ws;
    float* feat  = ws;                  // 6,400,000
    float* el    = feat + 6400000;      //   400,000
    float* er    = el + 400000;         //   400,000
    float* denom = er + 400000;         //   400,000
    float* rst   = denom + 400000;      // 6,400,000
    int*   offsets = (int*)(rst + 6400000);   // 50,000
    int*   cursor  = offsets + 50000;         // 50,000
    int*   deg     = cursor + 50000;          // 50,000
    int*   gctr    = deg + 50000;             // 16 (pad)
    int2*  srcw    = (int2*)(gctr + 16);      // 800,000 int2

    hipMemsetAsync(deg, 0, (50000 + 16) * sizeof(int), stream);  // deg + gctr

    k_fc<<<6250, 256, 0, stream>>>(x, Wfc, al, ar, feat, el, er);
    k_hist<<<N_EDGES / 256, 256, 0, stream>>>(dst, deg);
    k_alloc<<<196, 256, 0, stream>>>(deg, offsets, cursor, gctr);
    k_scatter<<<N_EDGES / 256, 256, 0, stream>>>(src, dst, w, cursor, srcw);
    k_gather<<<N_NODES / 8, 256, 0, stream>>>(srcw, offsets, deg, el, er, feat, denom, rst);
    k_out<<<6250, 256, 0, stream>>>(rst, denom, Wout, bout, out);
}